// Round 4
// baseline (344.323 us; speedup 1.0000x reference)
//
#include <hip/hip_runtime.h>
#include <hip/hip_fp16.h>
#include <math.h>

#define N_NODES 100000
#define N_EDGES 1600000
#define IN_DIM 128
#define F_DIM 128      // HEADS*OUT_DIM
#define NEG_SLOPE 0.2f

// ---- atomic-free CSR build parameters ----
#define BUCKW_LOG 7            // 128 nodes per bucket
#define NBUCK 784              // covers 100352 >= N_NODES
#define NBLK 800               // blocks in bucket passes
#define EPB 2000               // edges per block (NBLK*EPB == N_EDGES)
#define G_TOT (NBUCK * NBLK)   // 627200
#define SC_CHUNK 4096
#define SC_NB ((G_TOT + SC_CHUNK - 1) / SC_CHUNK)   // 154
#define CSR_CAP (N_EDGES + NBUCK * 128)             // padded slots

typedef short v8s __attribute__((ext_vector_type(8)));
typedef float v4f __attribute__((ext_vector_type(4)));

static __device__ __forceinline__ unsigned short f2bf(float f) {
    unsigned u = __float_as_uint(f);
    u += 0x7fffu + ((u >> 16) & 1u);
    return (unsigned short)(u >> 16);
}
static __device__ __forceinline__ float u2f(unsigned u) { return __uint_as_float(u); }
static __device__ __forceinline__ float bf2f(unsigned s) { return __uint_as_float(s << 16); }

// ---------------- W prep: Wt[n][k] = bf16(W[k][n]) ---------------------------
__global__ __launch_bounds__(256) void k_wprep(const float* __restrict__ W,
                                               unsigned short* __restrict__ Wt) {
    int i = blockIdx.x * 256 + threadIdx.x;   // 16384
    int n = i >> 7, k = i & 127;
    Wt[n * 128 + k] = f2bf(W[k * 128 + n]);
}

// ---------------- GEMM: h16 = bf16(x @ W) via MFMA ---------------------------
// Block: 64 rows x 128 cols, K=128 single-stage. 4 waves, each 16 rows.
__global__ __launch_bounds__(256) void k_gemm(const float* __restrict__ x,
                                              const unsigned short* __restrict__ Wt,
                                              unsigned short* __restrict__ h16) {
    __shared__ unsigned short As[64][136];    // [row][k], pad 8 -> 2-way max
    __shared__ unsigned short Bs[128][136];   // [n][k]
    const int t  = threadIdx.x;
    const int n0 = blockIdx.x * 64;

    // stage A: thread covers x[n0 + (t>>2)][ (t&3)*32 .. +32 ), cvt f32->bf16
    {
        int row = t >> 2, k0 = (t & 3) * 32;
        int n = n0 + row;
        #pragma unroll
        for (int i = 0; i < 4; i++) {
            float4 va = make_float4(0.f,0.f,0.f,0.f), vb = va;
            if (n < N_NODES) {
                const float* p = x + (size_t)n * IN_DIM + k0 + i * 8;
                va = *(const float4*)p;
                vb = *(const float4*)(p + 4);
            }
            uint4 u;
            u.x = f2bf(va.x) | ((unsigned)f2bf(va.y) << 16);
            u.y = f2bf(va.z) | ((unsigned)f2bf(va.w) << 16);
            u.z = f2bf(vb.x) | ((unsigned)f2bf(vb.y) << 16);
            u.w = f2bf(vb.z) | ((unsigned)f2bf(vb.w) << 16);
            *(uint4*)&As[row][k0 + i * 8] = u;
        }
    }
    // stage B: thread covers Wt[t>>1][ (t&1)*64 .. +64 )
    {
        int nr = t >> 1, s0 = (t & 1) * 64;
        const uint4* src = (const uint4*)(Wt + nr * 128 + s0);
        #pragma unroll
        for (int i = 0; i < 8; i++)
            *(uint4*)&Bs[nr][s0 + i * 8] = src[i];
    }
    __syncthreads();

    const int w = t >> 6, lane = t & 63;
    const int mr = lane & 15, quad = lane >> 4;
    const int m0 = w * 16;

    v4f acc[8];
    #pragma unroll
    for (int nt = 0; nt < 8; nt++) acc[nt] = (v4f){0.f, 0.f, 0.f, 0.f};

    #pragma unroll
    for (int kk = 0; kk < 4; kk++) {
        int kof = kk * 32 + quad * 8;
        v8s a = *(const v8s*)&As[m0 + mr][kof];
        #pragma unroll
        for (int nt = 0; nt < 8; nt++) {
            v8s b = *(const v8s*)&Bs[nt * 16 + mr][kof];
            acc[nt] = __builtin_amdgcn_mfma_f32_16x16x32_bf16(a, b, acc[nt], 0, 0, 0);
        }
    }

    // epilogue: bounce through own A rows (each wave only ever read its own rows)
    #pragma unroll
    for (int nt = 0; nt < 8; nt++)
        #pragma unroll
        for (int r = 0; r < 4; r++)
            As[m0 + quad * 4 + r][nt * 16 + mr] = f2bf(acc[nt][r]);
    __syncthreads();
    {
        int row = m0 + (lane >> 2);
        int c0  = (lane & 3) * 32;
        int n = n0 + row;
        if (n < N_NODES) {
            #pragma unroll
            for (int i = 0; i < 4; i++) {
                uint4 v = *(const uint4*)&As[row][c0 + i * 8];
                *(uint4*)&h16[(size_t)n * F_DIM + c0 + i * 8] = v;
            }
        }
    }
}

// ---------------- a_src / a_dst: one wave per node --------------------------
__global__ __launch_bounds__(256) void k_att(const unsigned* __restrict__ h16u,
                                             const float* __restrict__ att_src,
                                             const float* __restrict__ att_dst,
                                             float* __restrict__ a_src,
                                             float* __restrict__ a_dst) {
    int n = (blockIdx.x * 256 + threadIdx.x) >> 6;
    if (n >= N_NODES) return;
    int lane = threadIdx.x & 63;
    unsigned hv = h16u[n * 64 + lane];
    float hx = bf2f(hv & 0xffffu), hy = bf2f(hv >> 16);
    float2 av = *(const float2*)&att_src[2 * lane];
    float2 dv = *(const float2*)&att_dst[2 * lane];
    float s = hx * av.x + hy * av.y;
    float d = hx * dv.x + hy * dv.y;
    #pragma unroll
    for (int off = 1; off < 16; off <<= 1) {
        s += __shfl_xor(s, off, 64);
        d += __shfl_xor(d, off, 64);
    }
    if ((lane & 15) == 0) {
        int hd = lane >> 4;
        a_src[n * 4 + hd] = s;
        a_dst[n * 4 + hd] = d;
    }
}

// ---------------- CSR build, atomic-free (two-level counting sort) -----------
__global__ __launch_bounds__(256) void k_bhist(const int* __restrict__ ei_dst,
                                               int* __restrict__ G) {
    __shared__ int hist[NBUCK];
    for (int i = threadIdx.x; i < NBUCK; i += 256) hist[i] = 0;
    __syncthreads();
    int e0 = blockIdx.x * EPB;
    for (int i = threadIdx.x; i < EPB; i += 256) {
        int d = ei_dst[e0 + i];
        atomicAdd(&hist[d >> BUCKW_LOG], 1);
    }
    __syncthreads();
    for (int b = threadIdx.x; b < NBUCK; b += 256)
        G[b * NBLK + blockIdx.x] = hist[b];
}

__global__ __launch_bounds__(256) void k_scanp(const int* __restrict__ a,
                                               int* __restrict__ part) {
    int base = blockIdx.x * SC_CHUNK + threadIdx.x * 16;
    int s = 0;
    #pragma unroll
    for (int i = 0; i < 16; i++) {
        int idx = base + i;
        if (idx < G_TOT) s += a[idx];
    }
    __shared__ int wsum[4];
    for (int off = 32; off >= 1; off >>= 1) s += __shfl_down(s, off, 64);
    if ((threadIdx.x & 63) == 0) wsum[threadIdx.x >> 6] = s;
    __syncthreads();
    if (threadIdx.x == 0) part[blockIdx.x] = wsum[0] + wsum[1] + wsum[2] + wsum[3];
}

__global__ void k_scant(int* part, int* boff) {
    if (blockIdx.x == 0 && threadIdx.x == 0) {
        int run = 0;
        for (int b = 0; b < SC_NB; b++) { int v = part[b]; part[b] = run; run += v; }
        boff[NBUCK] = N_EDGES;
    }
}

__global__ __launch_bounds__(256) void k_scand(int* __restrict__ a,
                                               const int* __restrict__ part,
                                               int* __restrict__ boff) {
    __shared__ int tsum[256];
    int tid  = threadIdx.x;
    int base = blockIdx.x * SC_CHUNK + tid * 16;
    int v[16]; int s = 0;
    #pragma unroll
    for (int i = 0; i < 16; i++) {
        int idx = base + i;
        v[i] = (idx < G_TOT) ? a[idx] : 0;
        s += v[i];
    }
    tsum[tid] = s;
    __syncthreads();
    for (int off = 1; off < 256; off <<= 1) {
        int y = (tid >= off) ? tsum[tid - off] : 0;
        __syncthreads();
        tsum[tid] += y;
        __syncthreads();
    }
    int run = part[blockIdx.x] + tsum[tid] - s;
    #pragma unroll
    for (int i = 0; i < 16; i++) {
        int idx = base + i;
        if (idx < G_TOT) {
            a[idx] = run;
            if (idx % NBLK == 0) boff[idx / NBLK] = run;
        }
        run += v[i];
    }
}

// Pass C: scatter edges into bucket-grouped ebuf (pack src | local_dst<<17)
__global__ __launch_bounds__(256) void k_bscat(const int* __restrict__ ei,
                                               const int* __restrict__ G,
                                               int* __restrict__ ebuf) {
    __shared__ int base[NBUCK];
    for (int b = threadIdx.x; b < NBUCK; b += 256)
        base[b] = G[b * NBLK + blockIdx.x];
    __syncthreads();
    int e0 = blockIdx.x * EPB;
    for (int i = threadIdx.x; i < EPB; i += 256) {
        int s = ei[e0 + i];
        int d = ei[N_EDGES + e0 + i];
        int b = d >> BUCKW_LOG;
        int pos = atomicAdd(&base[b], 1);
        ebuf[pos] = s | ((d & 127) << 17);
    }
}

// Pass D: finalize. Per-node 2-aligned padded regions in csr2; per-edge
// attention weight p (4 heads, fp16) precomputed into pbuf.
__global__ __launch_bounds__(256) void k_csrfin(const int* __restrict__ ebuf,
                                                const int* __restrict__ boff,
                                                const float* __restrict__ a_src,
                                                const float* __restrict__ a_dst,
                                                int* __restrict__ ebeg,
                                                int* __restrict__ eend,
                                                int* __restrict__ csr2,
                                                __half* __restrict__ pbuf) {
    __shared__ int cnt[128];
    __shared__ int off[128];
    int b = blockIdx.x;
    int beg = boff[b], end = boff[b + 1];
    int padded_base = beg + b * 128;
    if (threadIdx.x < 128) cnt[threadIdx.x] = 0;
    __syncthreads();
    for (int j = beg + threadIdx.x; j < end; j += 256)
        atomicAdd(&cnt[(ebuf[j] >> 17) & 127], 1);
    __syncthreads();
    if (threadIdx.x == 0) {
        int run = padded_base;
        for (int i = 0; i < 128; i++) { off[i] = run; run += (cnt[i] + 1) & ~1; }
    }
    __syncthreads();
    if (threadIdx.x < 128) {
        int node = (b << BUCKW_LOG) + threadIdx.x;
        int c = cnt[threadIdx.x];
        if (node < N_NODES) {
            ebeg[node] = off[threadIdx.x];
            eend[node] = off[threadIdx.x] + c;
            if (c & 1) {                    // init pad slot: self idx, p = 0
                int pos = off[threadIdx.x] + c;
                csr2[pos] = node;
                *(uint2*)&pbuf[(size_t)pos * 4] = make_uint2(0u, 0u);
            }
        }
        cnt[threadIdx.x] = 0;               // reuse as cursors
    }
    __syncthreads();
    for (int j = beg + threadIdx.x; j < end; j += 256) {
        int p = ebuf[j];
        int dl = (p >> 17) & 127;
        int s = p & 0x1ffff;
        int r = atomicAdd(&cnt[dl], 1);
        int pos = off[dl] + r;
        csr2[pos] = s;
        int d = (b << BUCKW_LOG) + dl;
        float4 as = *(const float4*)&a_src[s * 4];
        float4 ad = *(const float4*)&a_dst[d * 4];
        float e0 = as.x + ad.x; e0 = e0 > 0.f ? e0 : NEG_SLOPE * e0;
        float e1 = as.y + ad.y; e1 = e1 > 0.f ? e1 : NEG_SLOPE * e1;
        float e2 = as.z + ad.z; e2 = e2 > 0.f ? e2 : NEG_SLOPE * e2;
        float e3 = as.w + ad.w; e3 = e3 > 0.f ? e3 : NEG_SLOPE * e3;
        __half2 lo = __floats2half2_rn(__expf(e0), __expf(e1));
        __half2 hi = __floats2half2_rn(__expf(e2), __expf(e3));
        *(uint2*)&pbuf[(size_t)pos * 4] =
            make_uint2(*(unsigned*)&lo, *(unsigned*)&hi);
    }
}

// ---------------- aggregation: one wave per dst, 2 edges/step ----------------
// lane: half=lane>>5, q=lane&31 -> owns features 4q..4q+3 (uint2 of h16),
// head hd=q>>3. Half 0 takes even slots (+ self-loop), half 1 odd slots.
// Cross-half combine via shfl_xor(32) at the end.
__global__ __launch_bounds__(256) void k_agg(const uint2* __restrict__ h16x2,
                                             const float* __restrict__ a_src,
                                             const float* __restrict__ a_dst,
                                             const int* __restrict__ ebeg,
                                             const int* __restrict__ eend,
                                             const int* __restrict__ csr2,
                                             const __half* __restrict__ pbuf,
                                             const float* __restrict__ bias,
                                             float* __restrict__ out) {
    int n = (blockIdx.x * 256 + threadIdx.x) >> 6;
    if (n >= N_NODES) return;
    int lane = threadIdx.x & 63;
    int half = lane >> 5, q = lane & 31, hd = q >> 3;

    // self-loop (half 0 only)
    float e0 = a_src[n * 4 + hd] + a_dst[n * 4 + hd];
    e0 = e0 > 0.f ? e0 : NEG_SLOPE * e0;
    float p0 = half ? 0.f : __expf(e0);
    uint2 hs = h16x2[(size_t)n * 32 + q];
    float l  = p0;
    float a0 = p0 * u2f(hs.x << 16);
    float a1 = p0 * u2f(hs.x & 0xffff0000u);
    float a2 = p0 * u2f(hs.y << 16);
    float a3 = p0 * u2f(hs.y & 0xffff0000u);

    int beg = ebeg[n], cnt = eend[n] - beg;
    const int2* cp = (const int2*)(csr2 + beg);    // beg is even
    int steps = (cnt + 1) >> 1;
    for (int t = 0; t < steps; t++) {
        int2 ss = cp[t];
        int s = half ? ss.y : ss.x;                 // pad slot holds self, p=0
        int slot = beg + 2 * t + half;
        float p = __half2float(pbuf[(size_t)slot * 4 + hd]);
        uint2 hh = h16x2[(size_t)s * 32 + q];
        l  += p;
        a0 += p * u2f(hh.x << 16);
        a1 += p * u2f(hh.x & 0xffff0000u);
        a2 += p * u2f(hh.y << 16);
        a3 += p * u2f(hh.y & 0xffff0000u);
    }
    // combine halves
    l  += __shfl_xor(l, 32, 64);
    a0 += __shfl_xor(a0, 32, 64);
    a1 += __shfl_xor(a1, 32, 64);
    a2 += __shfl_xor(a2, 32, 64);
    a3 += __shfl_xor(a3, 32, 64);

    if (half == 0) {
        float inv = 1.f / (l + 1e-16f);
        float4 bs = *(const float4*)&bias[q * 4];
        float o0 = a0 * inv + bs.x;
        float o1 = a1 * inv + bs.y;
        float o2 = a2 * inv + bs.z;
        float o3 = a3 * inv + bs.w;
        o0 = o0 > 0.f ? o0 : expm1f(o0);
        o1 = o1 > 0.f ? o1 : expm1f(o1);
        o2 = o2 > 0.f ? o2 : expm1f(o2);
        o3 = o3 > 0.f ? o3 : expm1f(o3);
        *(float4*)&out[(size_t)n * F_DIM + q * 4] = make_float4(o0, o1, o2, o3);
    }
}

extern "C" void kernel_launch(void* const* d_in, const int* in_sizes, int n_in,
                              void* d_out, int out_size, void* d_ws, size_t ws_size,
                              hipStream_t stream) {
    const float* x       = (const float*)d_in[0];
    const int*   ei      = (const int*)d_in[1];   // (2, E) row-major int32
    const float* W       = (const float*)d_in[2];
    const float* att_src = (const float*)d_in[3];
    const float* att_dst = (const float*)d_in[4];
    const float* bias    = (const float*)d_in[5];
    float*       out     = (float*)d_out;

    char* ws = (char*)d_ws;
    unsigned short* h16 = (unsigned short*)ws; ws += (size_t)N_NODES * F_DIM * 2;   // 25.6 MB
    unsigned short* Wt  = (unsigned short*)ws; ws += (size_t)IN_DIM * F_DIM * 2;    // 32 KB
    float* a_src  = (float*)ws; ws += (size_t)N_NODES * 4 * 4;
    float* a_dst  = (float*)ws; ws += (size_t)N_NODES * 4 * 4;
    int*   G      = (int*)ws;   ws += (size_t)G_TOT * 4;                            // 2.5 MB
    int*   part   = (int*)ws;   ws += 1024;
    int*   boff   = (int*)ws;   ws += 4096;
    int*   ebeg   = (int*)ws;   ws += (size_t)N_NODES * 4 + 512;
    int*   eend   = (int*)ws;   ws += (size_t)N_NODES * 4 + 512;
    int*   ebuf   = (int*)ws;   ws += (size_t)N_EDGES * 4;                          // 6.4 MB
    int*   csr2   = (int*)ws;   ws += (size_t)CSR_CAP * 4;                          // 6.8 MB
    __half* pbuf  = (__half*)ws; ws += (size_t)CSR_CAP * 4 * 2;                     // 13.6 MB

    k_wprep<<<64, 256, 0, stream>>>(W, Wt);
    k_gemm<<<(N_NODES + 63) / 64, 256, 0, stream>>>(x, Wt, h16);
    k_att<<<(N_NODES * 64 + 255) / 256, 256, 0, stream>>>((const unsigned*)h16, att_src, att_dst, a_src, a_dst);

    k_bhist<<<NBLK, 256, 0, stream>>>(ei + N_EDGES, G);
    k_scanp<<<SC_NB, 256, 0, stream>>>(G, part);
    k_scant<<<1, 64, 0, stream>>>(part, boff);
    k_scand<<<SC_NB, 256, 0, stream>>>(G, part, boff);
    k_bscat<<<NBLK, 256, 0, stream>>>(ei, G, ebuf);
    k_csrfin<<<NBUCK, 256, 0, stream>>>(ebuf, boff, a_src, a_dst, ebeg, eend, csr2, pbuf);

    k_agg<<<(N_NODES * 64 + 255) / 256, 256, 0, stream>>>((const uint2*)h16, a_src, a_dst, ebeg, eend, csr2, pbuf, bias, out);
}

// Round 5
// 302.039 us; speedup vs baseline: 1.1400x; 1.1400x over previous
//
#include <hip/hip_runtime.h>
#include <hip/hip_fp16.h>
#include <math.h>

#define N_NODES 100000
#define N_EDGES 1600000
#define IN_DIM 128
#define F_DIM 128      // HEADS*OUT_DIM
#define NEG_SLOPE 0.2f

// ---- atomic-free CSR build parameters ----
#define BUCKW_LOG 7            // 128 nodes per bucket
#define NBUCK 784              // covers 100352 >= N_NODES
#define NBLK 800               // blocks in bucket passes
#define EPB 2000               // edges per block (NBLK*EPB == N_EDGES)
#define G_TOT (NBUCK * NBLK)   // 627200
#define SC_CHUNK 4096
#define SC_NB ((G_TOT + SC_CHUNK - 1) / SC_CHUNK)   // 154
#define CSR_CAP (N_EDGES + NBUCK * 384)             // pad-to-4 slots (<=3/node)

typedef short v8s __attribute__((ext_vector_type(8)));
typedef float v4f __attribute__((ext_vector_type(4)));

static __device__ __forceinline__ unsigned short f2bf(float f) {
    unsigned u = __float_as_uint(f);
    u += 0x7fffu + ((u >> 16) & 1u);
    return (unsigned short)(u >> 16);
}
static __device__ __forceinline__ float bf2f(unsigned s) { return __uint_as_float(s << 16); }

// ---------------- W prep: Wt[n][k] = bf16(W[k][n]) ---------------------------
__global__ __launch_bounds__(256) void k_wprep(const float* __restrict__ W,
                                               unsigned short* __restrict__ Wt) {
    int i = blockIdx.x * 256 + threadIdx.x;   // 16384
    int n = i >> 7, k = i & 127;
    Wt[n * 128 + k] = f2bf(W[k * 128 + n]);
}

// ---------------- GEMM: h16 = bf16(x @ W) via MFMA, fused a_src/a_dst --------
// Block: 64 rows x 128 cols, K=128 single-stage. 4 waves, each 16 rows.
// Epilogue also computes a_src[n][h], a_dst[n][h] from the LDS-resident h tile.
__global__ __launch_bounds__(256) void k_gemm(const float* __restrict__ x,
                                              const unsigned short* __restrict__ Wt,
                                              unsigned short* __restrict__ h16,
                                              const float* __restrict__ att_src,
                                              const float* __restrict__ att_dst,
                                              float* __restrict__ a_src,
                                              float* __restrict__ a_dst) {
    __shared__ unsigned short As[64][136];    // [row][k]
    __shared__ unsigned short Bs[128][136];   // [n][k]
    __shared__ float attl[256];               // [0..127]=att_src, [128..255]=att_dst
    const int t  = threadIdx.x;
    const int n0 = blockIdx.x * 64;

    attl[t] = (t < 128) ? att_src[t] : att_dst[t - 128];

    // stage A: thread covers x[n0 + (t>>2)][ (t&3)*32 .. +32 ), cvt f32->bf16
    {
        int row = t >> 2, k0 = (t & 3) * 32;
        int n = n0 + row;
        #pragma unroll
        for (int i = 0; i < 4; i++) {
            float4 va = make_float4(0.f,0.f,0.f,0.f), vb = va;
            if (n < N_NODES) {
                const float* p = x + (size_t)n * IN_DIM + k0 + i * 8;
                va = *(const float4*)p;
                vb = *(const float4*)(p + 4);
            }
            uint4 u;
            u.x = f2bf(va.x) | ((unsigned)f2bf(va.y) << 16);
            u.y = f2bf(va.z) | ((unsigned)f2bf(va.w) << 16);
            u.z = f2bf(vb.x) | ((unsigned)f2bf(vb.y) << 16);
            u.w = f2bf(vb.z) | ((unsigned)f2bf(vb.w) << 16);
            *(uint4*)&As[row][k0 + i * 8] = u;
        }
    }
    // stage B: thread covers Wt[t>>1][ (t&1)*64 .. +64 )
    {
        int nr = t >> 1, s0 = (t & 1) * 64;
        const uint4* src = (const uint4*)(Wt + nr * 128 + s0);
        #pragma unroll
        for (int i = 0; i < 8; i++)
            *(uint4*)&Bs[nr][s0 + i * 8] = src[i];
    }
    __syncthreads();

    const int w = t >> 6, lane = t & 63;
    const int mr = lane & 15, quad = lane >> 4;
    const int m0 = w * 16;

    v4f acc[8];
    #pragma unroll
    for (int nt = 0; nt < 8; nt++) acc[nt] = (v4f){0.f, 0.f, 0.f, 0.f};

    #pragma unroll
    for (int kk = 0; kk < 4; kk++) {
        int kof = kk * 32 + quad * 8;
        v8s a = *(const v8s*)&As[m0 + mr][kof];
        #pragma unroll
        for (int nt = 0; nt < 8; nt++) {
            v8s b = *(const v8s*)&Bs[nt * 16 + mr][kof];
            acc[nt] = __builtin_amdgcn_mfma_f32_16x16x32_bf16(a, b, acc[nt], 0, 0, 0);
        }
    }

    // epilogue: bounce through own A rows
    #pragma unroll
    for (int nt = 0; nt < 8; nt++)
        #pragma unroll
        for (int r = 0; r < 4; r++)
            As[m0 + quad * 4 + r][nt * 16 + mr] = f2bf(acc[nt][r]);
    __syncthreads();
    {
        int row = m0 + (lane >> 2);       // wave covers rows m0..m0+15
        int c0  = (lane & 3) * 32;        // 32 cols = one head
        int n = n0 + row;
        if (n < N_NODES) {
            float ds = 0.f, dd = 0.f;
            #pragma unroll
            for (int i = 0; i < 4; i++) {
                uint4 v = *(const uint4*)&As[row][c0 + i * 8];
                *(uint4*)&h16[(size_t)n * F_DIM + c0 + i * 8] = v;
                float f0 = bf2f(v.x & 0xffffu), f1 = bf2f(v.x >> 16);
                float f2 = bf2f(v.y & 0xffffu), f3 = bf2f(v.y >> 16);
                float f4 = bf2f(v.z & 0xffffu), f5 = bf2f(v.z >> 16);
                float f6 = bf2f(v.w & 0xffffu), f7 = bf2f(v.w >> 16);
                const float* ps = &attl[c0 + i * 8];
                const float* pd = &attl[128 + c0 + i * 8];
                ds += f0*ps[0] + f1*ps[1] + f2*ps[2] + f3*ps[3]
                    + f4*ps[4] + f5*ps[5] + f6*ps[6] + f7*ps[7];
                dd += f0*pd[0] + f1*pd[1] + f2*pd[2] + f3*pd[3]
                    + f4*pd[4] + f5*pd[5] + f6*pd[6] + f7*pd[7];
            }
            int hd = lane & 3;
            a_src[n * 4 + hd] = ds;
            a_dst[n * 4 + hd] = dd;
        }
    }
}

// ---------------- CSR build, atomic-free (two-level counting sort) -----------
__global__ __launch_bounds__(256) void k_bhist(const int* __restrict__ ei_dst,
                                               int* __restrict__ G) {
    __shared__ int hist[NBUCK];
    for (int i = threadIdx.x; i < NBUCK; i += 256) hist[i] = 0;
    __syncthreads();
    int e0 = blockIdx.x * EPB;
    for (int i = threadIdx.x; i < EPB; i += 256) {
        int d = ei_dst[e0 + i];
        atomicAdd(&hist[d >> BUCKW_LOG], 1);
    }
    __syncthreads();
    for (int b = threadIdx.x; b < NBUCK; b += 256)
        G[b * NBLK + blockIdx.x] = hist[b];
}

__global__ __launch_bounds__(256) void k_scanp(const int* __restrict__ a,
                                               int* __restrict__ part) {
    int base = blockIdx.x * SC_CHUNK + threadIdx.x * 16;
    int s = 0;
    #pragma unroll
    for (int i = 0; i < 16; i++) {
        int idx = base + i;
        if (idx < G_TOT) s += a[idx];
    }
    __shared__ int wsum[4];
    for (int off = 32; off >= 1; off >>= 1) s += __shfl_down(s, off, 64);
    if ((threadIdx.x & 63) == 0) wsum[threadIdx.x >> 6] = s;
    __syncthreads();
    if (threadIdx.x == 0) part[blockIdx.x] = wsum[0] + wsum[1] + wsum[2] + wsum[3];
}

__global__ void k_scant(int* part, int* boff) {
    if (blockIdx.x == 0 && threadIdx.x == 0) {
        int run = 0;
        for (int b = 0; b < SC_NB; b++) { int v = part[b]; part[b] = run; run += v; }
        boff[NBUCK] = N_EDGES;
    }
}

__global__ __launch_bounds__(256) void k_scand(int* __restrict__ a,
                                               const int* __restrict__ part,
                                               int* __restrict__ boff) {
    __shared__ int tsum[256];
    int tid  = threadIdx.x;
    int base = blockIdx.x * SC_CHUNK + tid * 16;
    int v[16]; int s = 0;
    #pragma unroll
    for (int i = 0; i < 16; i++) {
        int idx = base + i;
        v[i] = (idx < G_TOT) ? a[idx] : 0;
        s += v[i];
    }
    tsum[tid] = s;
    __syncthreads();
    for (int off = 1; off < 256; off <<= 1) {
        int y = (tid >= off) ? tsum[tid - off] : 0;
        __syncthreads();
        tsum[tid] += y;
        __syncthreads();
    }
    int run = part[blockIdx.x] + tsum[tid] - s;
    #pragma unroll
    for (int i = 0; i < 16; i++) {
        int idx = base + i;
        if (idx < G_TOT) {
            a[idx] = run;
            if (idx % NBLK == 0) boff[idx / NBLK] = run;
        }
        run += v[i];
    }
}

// Pass C: scatter edges into bucket-grouped ebuf (pack src | local_dst<<17)
__global__ __launch_bounds__(256) void k_bscat(const int* __restrict__ ei,
                                               const int* __restrict__ G,
                                               int* __restrict__ ebuf) {
    __shared__ int base[NBUCK];
    for (int b = threadIdx.x; b < NBUCK; b += 256)
        base[b] = G[b * NBLK + blockIdx.x];
    __syncthreads();
    int e0 = blockIdx.x * EPB;
    for (int i = threadIdx.x; i < EPB; i += 256) {
        int s = ei[e0 + i];
        int d = ei[N_EDGES + e0 + i];
        int b = d >> BUCKW_LOG;
        int pos = atomicAdd(&base[b], 1);
        ebuf[pos] = s | ((d & 127) << 17);
    }
}

// Pass D: finalize. Per-node 4-aligned padded regions in csr2; per-edge
// attention weight p (4 heads, fp16) precomputed into pbuf.
__global__ __launch_bounds__(256) void k_csrfin(const int* __restrict__ ebuf,
                                                const int* __restrict__ boff,
                                                const float* __restrict__ a_src,
                                                const float* __restrict__ a_dst,
                                                int* __restrict__ ebeg,
                                                int* __restrict__ eend,
                                                int* __restrict__ csr2,
                                                __half* __restrict__ pbuf) {
    __shared__ int cnt[128];
    __shared__ int off[128];
    int b = blockIdx.x;
    int beg = boff[b], end = boff[b + 1];
    int padded_base = beg + b * 384;     // reserve 3 pad slots per node
    if (threadIdx.x < 128) cnt[threadIdx.x] = 0;
    __syncthreads();
    for (int j = beg + threadIdx.x; j < end; j += 256)
        atomicAdd(&cnt[(ebuf[j] >> 17) & 127], 1);
    __syncthreads();
    if (threadIdx.x == 0) {
        int run = padded_base;
        for (int i = 0; i < 128; i++) { off[i] = run; run += (cnt[i] + 3) & ~3; }
    }
    __syncthreads();
    if (threadIdx.x < 128) {
        int node = (b << BUCKW_LOG) + threadIdx.x;
        int c = cnt[threadIdx.x];
        if (node < N_NODES) {
            ebeg[node] = off[threadIdx.x];
            eend[node] = off[threadIdx.x] + c;
            int cpad = (c + 3) & ~3;
            for (int k = c; k < cpad; k++) {     // pad slots: self idx, p = 0
                int pos = off[threadIdx.x] + k;
                csr2[pos] = node;
                *(uint2*)&pbuf[(size_t)pos * 4] = make_uint2(0u, 0u);
            }
        }
        cnt[threadIdx.x] = 0;               // reuse as cursors
    }
    __syncthreads();
    for (int j = beg + threadIdx.x; j < end; j += 256) {
        int p = ebuf[j];
        int dl = (p >> 17) & 127;
        int s = p & 0x1ffff;
        int r = atomicAdd(&cnt[dl], 1);
        int pos = off[dl] + r;
        csr2[pos] = s;
        int d = (b << BUCKW_LOG) + dl;
        float4 as = *(const float4*)&a_src[s * 4];
        float4 ad = *(const float4*)&a_dst[d * 4];
        float e0 = as.x + ad.x; e0 = e0 > 0.f ? e0 : NEG_SLOPE * e0;
        float e1 = as.y + ad.y; e1 = e1 > 0.f ? e1 : NEG_SLOPE * e1;
        float e2 = as.z + ad.z; e2 = e2 > 0.f ? e2 : NEG_SLOPE * e2;
        float e3 = as.w + ad.w; e3 = e3 > 0.f ? e3 : NEG_SLOPE * e3;
        __half2 lo = __floats2half2_rn(__expf(e0), __expf(e1));
        __half2 hi = __floats2half2_rn(__expf(e2), __expf(e3));
        *(uint2*)&pbuf[(size_t)pos * 4] =
            make_uint2(*(unsigned*)&lo, *(unsigned*)&hi);
    }
}

// ---------------- aggregation: one wave per dst, 4 edges/step, unroll 2 ------
// 16-lane group grp=lane>>4 owns one edge per step; lane g=lane&15 owns
// features g*8..g*8+7 (uint4 of h16), head hd=g>>2. 8 edge-row gathers in
// flight per wave. Cross-group combine via shfl_xor(16,32) at the end.
__global__ __launch_bounds__(256) void k_agg(const uint4* __restrict__ h16x4,
                                             const float* __restrict__ a_src,
                                             const float* __restrict__ a_dst,
                                             const int* __restrict__ ebeg,
                                             const int* __restrict__ eend,
                                             const int* __restrict__ csr2,
                                             const __half* __restrict__ pbuf,
                                             const float* __restrict__ bias,
                                             float* __restrict__ out) {
    int n = (blockIdx.x * 256 + threadIdx.x) >> 6;
    if (n >= N_NODES) return;
    int lane = threadIdx.x & 63;
    int grp = lane >> 4, g = lane & 15, hd = g >> 2;

    float p0 = 0.f;
    if (grp == 0) {
        float e0 = a_src[n * 4 + hd] + a_dst[n * 4 + hd];
        e0 = e0 > 0.f ? e0 : NEG_SLOPE * e0;
        p0 = __expf(e0);                   // self-loop (group 0 only)
    }
    uint4 hs = h16x4[(size_t)n * 16 + g];
    float l  = p0;
    float a0 = p0 * bf2f(hs.x & 0xffffu), a1 = p0 * bf2f(hs.x >> 16);
    float a2 = p0 * bf2f(hs.y & 0xffffu), a3 = p0 * bf2f(hs.y >> 16);
    float a4 = p0 * bf2f(hs.z & 0xffffu), a5 = p0 * bf2f(hs.z >> 16);
    float a6 = p0 * bf2f(hs.w & 0xffffu), a7 = p0 * bf2f(hs.w >> 16);

    int beg = ebeg[n], cnt = eend[n] - beg;
    const int* sp = csr2 + beg + grp;
    const __half* pp = pbuf + (size_t)(beg + grp) * 4 + hd;
    int steps = (cnt + 3) >> 2;
    int t = 0;
    for (; t + 2 <= steps; t += 2) {
        int s0 = sp[4 * t];
        int s1 = sp[4 * t + 4];
        float q0 = __half2float(pp[16 * t]);
        float q1 = __half2float(pp[16 * t + 16]);
        uint4 h0 = h16x4[(size_t)s0 * 16 + g];
        uint4 h1 = h16x4[(size_t)s1 * 16 + g];
        l  += q0 + q1;
        a0 += q0 * bf2f(h0.x & 0xffffu) + q1 * bf2f(h1.x & 0xffffu);
        a1 += q0 * bf2f(h0.x >> 16)     + q1 * bf2f(h1.x >> 16);
        a2 += q0 * bf2f(h0.y & 0xffffu) + q1 * bf2f(h1.y & 0xffffu);
        a3 += q0 * bf2f(h0.y >> 16)     + q1 * bf2f(h1.y >> 16);
        a4 += q0 * bf2f(h0.z & 0xffffu) + q1 * bf2f(h1.z & 0xffffu);
        a5 += q0 * bf2f(h0.z >> 16)     + q1 * bf2f(h1.z >> 16);
        a6 += q0 * bf2f(h0.w & 0xffffu) + q1 * bf2f(h1.w & 0xffffu);
        a7 += q0 * bf2f(h0.w >> 16)     + q1 * bf2f(h1.w >> 16);
    }
    if (t < steps) {
        int s0 = sp[4 * t];
        float q0 = __half2float(pp[16 * t]);
        uint4 h0 = h16x4[(size_t)s0 * 16 + g];
        l  += q0;
        a0 += q0 * bf2f(h0.x & 0xffffu);
        a1 += q0 * bf2f(h0.x >> 16);
        a2 += q0 * bf2f(h0.y & 0xffffu);
        a3 += q0 * bf2f(h0.y >> 16);
        a4 += q0 * bf2f(h0.z & 0xffffu);
        a5 += q0 * bf2f(h0.z >> 16);
        a6 += q0 * bf2f(h0.w & 0xffffu);
        a7 += q0 * bf2f(h0.w >> 16);
    }
    #define RED2(v) v += __shfl_xor(v, 16, 64); v += __shfl_xor(v, 32, 64);
    RED2(l); RED2(a0); RED2(a1); RED2(a2); RED2(a3);
    RED2(a4); RED2(a5); RED2(a6); RED2(a7);
    #undef RED2

    if (grp == 0) {
        float inv = 1.f / (l + 1e-16f);
        float4 b0 = *(const float4*)&bias[g * 8];
        float4 b1 = *(const float4*)&bias[g * 8 + 4];
        float o0 = a0 * inv + b0.x, o1 = a1 * inv + b0.y;
        float o2 = a2 * inv + b0.z, o3 = a3 * inv + b0.w;
        float o4 = a4 * inv + b1.x, o5 = a5 * inv + b1.y;
        float o6 = a6 * inv + b1.z, o7 = a7 * inv + b1.w;
        o0 = o0 > 0.f ? o0 : expm1f(o0);
        o1 = o1 > 0.f ? o1 : expm1f(o1);
        o2 = o2 > 0.f ? o2 : expm1f(o2);
        o3 = o3 > 0.f ? o3 : expm1f(o3);
        o4 = o4 > 0.f ? o4 : expm1f(o4);
        o5 = o5 > 0.f ? o5 : expm1f(o5);
        o6 = o6 > 0.f ? o6 : expm1f(o6);
        o7 = o7 > 0.f ? o7 : expm1f(o7);
        *(float4*)&out[(size_t)n * F_DIM + g * 8]     = make_float4(o0, o1, o2, o3);
        *(float4*)&out[(size_t)n * F_DIM + g * 8 + 4] = make_float4(o4, o5, o6, o7);
    }
}

extern "C" void kernel_launch(void* const* d_in, const int* in_sizes, int n_in,
                              void* d_out, int out_size, void* d_ws, size_t ws_size,
                              hipStream_t stream) {
    const float* x       = (const float*)d_in[0];
    const int*   ei      = (const int*)d_in[1];   // (2, E) row-major int32
    const float* W       = (const float*)d_in[2];
    const float* att_src = (const float*)d_in[3];
    const float* att_dst = (const float*)d_in[4];
    const float* bias    = (const float*)d_in[5];
    float*       out     = (float*)d_out;

    char* ws = (char*)d_ws;
    unsigned short* h16 = (unsigned short*)ws; ws += (size_t)N_NODES * F_DIM * 2;   // 25.6 MB
    unsigned short* Wt  = (unsigned short*)ws; ws += (size_t)IN_DIM * F_DIM * 2;    // 32 KB
    float* a_src  = (float*)ws; ws += (size_t)N_NODES * 4 * 4;
    float* a_dst  = (float*)ws; ws += (size_t)N_NODES * 4 * 4;
    int*   G      = (int*)ws;   ws += (size_t)G_TOT * 4;                            // 2.5 MB
    int*   part   = (int*)ws;   ws += 1024;
    int*   boff   = (int*)ws;   ws += 4096;
    int*   ebeg   = (int*)ws;   ws += (size_t)N_NODES * 4 + 512;
    int*   eend   = (int*)ws;   ws += (size_t)N_NODES * 4 + 512;
    int*   ebuf   = (int*)ws;   ws += (size_t)N_EDGES * 4;                          // 6.4 MB
    int*   csr2   = (int*)ws;   ws += (size_t)CSR_CAP * 4;                          // 7.6 MB
    __half* pbuf  = (__half*)ws; ws += (size_t)CSR_CAP * 4 * 2;                     // 15.2 MB

    k_wprep<<<64, 256, 0, stream>>>(W, Wt);
    k_gemm<<<(N_NODES + 63) / 64, 256, 0, stream>>>(x, Wt, h16, att_src, att_dst, a_src, a_dst);

    k_bhist<<<NBLK, 256, 0, stream>>>(ei + N_EDGES, G);
    k_scanp<<<SC_NB, 256, 0, stream>>>(G, part);
    k_scant<<<1, 64, 0, stream>>>(part, boff);
    k_scand<<<SC_NB, 256, 0, stream>>>(G, part, boff);
    k_bscat<<<NBLK, 256, 0, stream>>>(ei, G, ebuf);
    k_csrfin<<<NBUCK, 256, 0, stream>>>(ebuf, boff, a_src, a_dst, ebeg, eend, csr2, pbuf);

    k_agg<<<(N_NODES * 64 + 255) / 256, 256, 0, stream>>>((const uint4*)h16, a_src, a_dst, ebeg, eend, csr2, pbuf, bias, out);
}

// Round 6
// 301.050 us; speedup vs baseline: 1.1437x; 1.0033x over previous
//
#include <hip/hip_runtime.h>
#include <hip/hip_fp16.h>
#include <math.h>

#define N_NODES 100000
#define N_EDGES 1600000
#define IN_DIM 128
#define F_DIM 128      // HEADS*OUT_DIM
#define NEG_SLOPE 0.2f

// ---- atomic-free CSR build parameters ----
#define BUCKW_LOG 7            // 128 nodes per bucket
#define NBUCK 784              // covers 100352 >= N_NODES
#define NBLK 128               // blocks in bucket passes
#define EPB 12500              // edges per block (NBLK*EPB == N_EDGES); runs ~16 edges = 64B line
#define G_TOT (NBUCK * NBLK)   // 100352
#define SC_CHUNK 4096
#define SC_NB ((G_TOT + SC_CHUNK - 1) / SC_CHUNK)   // 25 (fits one wave in k_scant)
#define CSR_CAP (N_EDGES + NBUCK * 384)             // pad-to-4 slots (<=3/node)

typedef short v8s __attribute__((ext_vector_type(8)));
typedef float v4f __attribute__((ext_vector_type(4)));

static __device__ __forceinline__ unsigned short f2bf(float f) {
    unsigned u = __float_as_uint(f);
    u += 0x7fffu + ((u >> 16) & 1u);
    return (unsigned short)(u >> 16);
}
static __device__ __forceinline__ float bf2f(unsigned s) { return __uint_as_float(s << 16); }
static __device__ __forceinline__ float lo2f(unsigned u) { return __uint_as_float(u << 16); }
static __device__ __forceinline__ float hi2f(unsigned u) { return __uint_as_float(u & 0xffff0000u); }

// ---------------- W prep: Wt[n][k] = bf16(W[k][n]) ---------------------------
__global__ __launch_bounds__(256) void k_wprep(const float* __restrict__ W,
                                               unsigned short* __restrict__ Wt) {
    int i = blockIdx.x * 256 + threadIdx.x;   // 16384
    int n = i >> 7, k = i & 127;
    Wt[n * 128 + k] = f2bf(W[k * 128 + n]);
}

// ---------------- GEMM: h16 = bf16(x @ W) via MFMA, fused a_src/a_dst --------
__global__ __launch_bounds__(256) void k_gemm(const float* __restrict__ x,
                                              const unsigned short* __restrict__ Wt,
                                              unsigned short* __restrict__ h16,
                                              const float* __restrict__ att_src,
                                              const float* __restrict__ att_dst,
                                              float* __restrict__ a_src,
                                              float* __restrict__ a_dst) {
    __shared__ unsigned short As[64][136];    // [row][k]
    __shared__ unsigned short Bs[128][136];   // [n][k]
    __shared__ float attl[256];               // [0..127]=att_src, [128..255]=att_dst
    const int t  = threadIdx.x;
    const int n0 = blockIdx.x * 64;

    attl[t] = (t < 128) ? att_src[t] : att_dst[t - 128];

    {
        int row = t >> 2, k0 = (t & 3) * 32;
        int n = n0 + row;
        #pragma unroll
        for (int i = 0; i < 4; i++) {
            float4 va = make_float4(0.f,0.f,0.f,0.f), vb = va;
            if (n < N_NODES) {
                const float* p = x + (size_t)n * IN_DIM + k0 + i * 8;
                va = *(const float4*)p;
                vb = *(const float4*)(p + 4);
            }
            uint4 u;
            u.x = f2bf(va.x) | ((unsigned)f2bf(va.y) << 16);
            u.y = f2bf(va.z) | ((unsigned)f2bf(va.w) << 16);
            u.z = f2bf(vb.x) | ((unsigned)f2bf(vb.y) << 16);
            u.w = f2bf(vb.z) | ((unsigned)f2bf(vb.w) << 16);
            *(uint4*)&As[row][k0 + i * 8] = u;
        }
    }
    {
        int nr = t >> 1, s0 = (t & 1) * 64;
        const uint4* src = (const uint4*)(Wt + nr * 128 + s0);
        #pragma unroll
        for (int i = 0; i < 8; i++)
            *(uint4*)&Bs[nr][s0 + i * 8] = src[i];
    }
    __syncthreads();

    const int w = t >> 6, lane = t & 63;
    const int mr = lane & 15, quad = lane >> 4;
    const int m0 = w * 16;

    v4f acc[8];
    #pragma unroll
    for (int nt = 0; nt < 8; nt++) acc[nt] = (v4f){0.f, 0.f, 0.f, 0.f};

    #pragma unroll
    for (int kk = 0; kk < 4; kk++) {
        int kof = kk * 32 + quad * 8;
        v8s a = *(const v8s*)&As[m0 + mr][kof];
        #pragma unroll
        for (int nt = 0; nt < 8; nt++) {
            v8s b = *(const v8s*)&Bs[nt * 16 + mr][kof];
            acc[nt] = __builtin_amdgcn_mfma_f32_16x16x32_bf16(a, b, acc[nt], 0, 0, 0);
        }
    }

    #pragma unroll
    for (int nt = 0; nt < 8; nt++)
        #pragma unroll
        for (int r = 0; r < 4; r++)
            As[m0 + quad * 4 + r][nt * 16 + mr] = f2bf(acc[nt][r]);
    __syncthreads();
    {
        int row = m0 + (lane >> 2);
        int c0  = (lane & 3) * 32;        // 32 cols = one head
        int n = n0 + row;
        if (n < N_NODES) {
            float ds = 0.f, dd = 0.f;
            #pragma unroll
            for (int i = 0; i < 4; i++) {
                uint4 v = *(const uint4*)&As[row][c0 + i * 8];
                *(uint4*)&h16[(size_t)n * F_DIM + c0 + i * 8] = v;
                float f0 = lo2f(v.x), f1 = hi2f(v.x);
                float f2 = lo2f(v.y), f3 = hi2f(v.y);
                float f4 = lo2f(v.z), f5 = hi2f(v.z);
                float f6 = lo2f(v.w), f7 = hi2f(v.w);
                const float* ps = &attl[c0 + i * 8];
                const float* pd = &attl[128 + c0 + i * 8];
                ds += f0*ps[0] + f1*ps[1] + f2*ps[2] + f3*ps[3]
                    + f4*ps[4] + f5*ps[5] + f6*ps[6] + f7*ps[7];
                dd += f0*pd[0] + f1*pd[1] + f2*pd[2] + f3*pd[3]
                    + f4*pd[4] + f5*pd[5] + f6*pd[6] + f7*pd[7];
            }
            int hd = lane & 3;
            a_src[n * 4 + hd] = ds;
            a_dst[n * 4 + hd] = dd;
        }
    }
}

// ---------------- CSR build, atomic-free (two-level counting sort) -----------
__global__ __launch_bounds__(256) void k_bhist(const int* __restrict__ ei_dst,
                                               int* __restrict__ G) {
    __shared__ int hist[NBUCK];
    for (int i = threadIdx.x; i < NBUCK; i += 256) hist[i] = 0;
    __syncthreads();
    int e0 = blockIdx.x * EPB;
    for (int i = threadIdx.x; i < EPB; i += 256) {
        int d = ei_dst[e0 + i];
        atomicAdd(&hist[d >> BUCKW_LOG], 1);
    }
    __syncthreads();
    for (int b = threadIdx.x; b < NBUCK; b += 256)
        G[b * NBLK + blockIdx.x] = hist[b];
}

__global__ __launch_bounds__(256) void k_scanp(const int* __restrict__ a,
                                               int* __restrict__ part) {
    int base = blockIdx.x * SC_CHUNK + threadIdx.x * 16;
    int s = 0;
    #pragma unroll
    for (int i = 0; i < 16; i++) {
        int idx = base + i;
        if (idx < G_TOT) s += a[idx];
    }
    __shared__ int wsum[4];
    for (int off = 32; off >= 1; off >>= 1) s += __shfl_down(s, off, 64);
    if ((threadIdx.x & 63) == 0) wsum[threadIdx.x >> 6] = s;
    __syncthreads();
    if (threadIdx.x == 0) part[blockIdx.x] = wsum[0] + wsum[1] + wsum[2] + wsum[3];
}

// one-wave shuffle scan over SC_NB (<=64) partials
__global__ void k_scant(int* part, int* boff) {
    int lane = threadIdx.x & 63;
    int v = (lane < SC_NB) ? part[lane] : 0;
    int x = v;
    #pragma unroll
    for (int off = 1; off < 64; off <<= 1) {
        int y = __shfl_up(x, off, 64);
        if (lane >= off) x += y;
    }
    if (lane < SC_NB) part[lane] = x - v;   // exclusive
    if (lane == 0) boff[NBUCK] = N_EDGES;
}

__global__ __launch_bounds__(256) void k_scand(int* __restrict__ a,
                                               const int* __restrict__ part,
                                               int* __restrict__ boff) {
    __shared__ int tsum[256];
    int tid  = threadIdx.x;
    int base = blockIdx.x * SC_CHUNK + tid * 16;
    int v[16]; int s = 0;
    #pragma unroll
    for (int i = 0; i < 16; i++) {
        int idx = base + i;
        v[i] = (idx < G_TOT) ? a[idx] : 0;
        s += v[i];
    }
    tsum[tid] = s;
    __syncthreads();
    for (int off = 1; off < 256; off <<= 1) {
        int y = (tid >= off) ? tsum[tid - off] : 0;
        __syncthreads();
        tsum[tid] += y;
        __syncthreads();
    }
    int run = part[blockIdx.x] + tsum[tid] - s;
    #pragma unroll
    for (int i = 0; i < 16; i++) {
        int idx = base + i;
        if (idx < G_TOT) {
            a[idx] = run;
            if (idx % NBLK == 0) boff[idx / NBLK] = run;
        }
        run += v[i];
    }
}

// Pass C: scatter edges into bucket-grouped ebuf (pack src | local_dst<<17)
__global__ __launch_bounds__(256) void k_bscat(const int* __restrict__ ei,
                                               const int* __restrict__ G,
                                               int* __restrict__ ebuf) {
    __shared__ int base[NBUCK];
    for (int b = threadIdx.x; b < NBUCK; b += 256)
        base[b] = G[b * NBLK + blockIdx.x];
    __syncthreads();
    int e0 = blockIdx.x * EPB;
    for (int i = threadIdx.x; i < EPB; i += 256) {
        int s = ei[e0 + i];
        int d = ei[N_EDGES + e0 + i];
        int b = d >> BUCKW_LOG;
        int pos = atomicAdd(&base[b], 1);
        ebuf[pos] = s | ((d & 127) << 17);
    }
}

// Pass D: finalize. Per-node 4-aligned padded regions in csr2; per-edge
// attention weight p (4 heads, fp16) precomputed into pbuf.
__global__ __launch_bounds__(256) void k_csrfin(const int* __restrict__ ebuf,
                                                const int* __restrict__ boff,
                                                const float* __restrict__ a_src,
                                                const float* __restrict__ a_dst,
                                                int2* __restrict__ ebounds,
                                                int* __restrict__ csr2,
                                                __half* __restrict__ pbuf) {
    __shared__ int cnt[128];
    __shared__ int off[128];
    int b = blockIdx.x;
    int beg = boff[b], end = boff[b + 1];
    int padded_base = beg + b * 384;     // reserve 3 pad slots per node
    if (threadIdx.x < 128) cnt[threadIdx.x] = 0;
    __syncthreads();
    for (int j = beg + threadIdx.x; j < end; j += 256)
        atomicAdd(&cnt[(ebuf[j] >> 17) & 127], 1);
    __syncthreads();
    if (threadIdx.x == 0) {
        int run = padded_base;
        for (int i = 0; i < 128; i++) { off[i] = run; run += (cnt[i] + 3) & ~3; }
    }
    __syncthreads();
    if (threadIdx.x < 128) {
        int node = (b << BUCKW_LOG) + threadIdx.x;
        int c = cnt[threadIdx.x];
        if (node < N_NODES) {
            ebounds[node] = make_int2(off[threadIdx.x], off[threadIdx.x] + c);
            int cpad = (c + 3) & ~3;
            for (int k = c; k < cpad; k++) {     // pad slots: self idx, p = 0
                int pos = off[threadIdx.x] + k;
                csr2[pos] = node;
                *(uint2*)&pbuf[(size_t)pos * 4] = make_uint2(0u, 0u);
            }
        }
        cnt[threadIdx.x] = 0;               // reuse as cursors
    }
    __syncthreads();
    for (int j = beg + threadIdx.x; j < end; j += 256) {
        int p = ebuf[j];
        int dl = (p >> 17) & 127;
        int s = p & 0x1ffff;
        int r = atomicAdd(&cnt[dl], 1);
        int pos = off[dl] + r;
        csr2[pos] = s;
        int d = (b << BUCKW_LOG) + dl;
        float4 as = *(const float4*)&a_src[s * 4];
        float4 ad = *(const float4*)&a_dst[d * 4];
        float e0 = as.x + ad.x; e0 = e0 > 0.f ? e0 : NEG_SLOPE * e0;
        float e1 = as.y + ad.y; e1 = e1 > 0.f ? e1 : NEG_SLOPE * e1;
        float e2 = as.z + ad.z; e2 = e2 > 0.f ? e2 : NEG_SLOPE * e2;
        float e3 = as.w + ad.w; e3 = e3 > 0.f ? e3 : NEG_SLOPE * e3;
        __half2 lo = __floats2half2_rn(__expf(e0), __expf(e1));
        __half2 hi = __floats2half2_rn(__expf(e2), __expf(e3));
        *(uint2*)&pbuf[(size_t)pos * 4] =
            make_uint2(*(unsigned*)&lo, *(unsigned*)&hi);
    }
}

// ---------------- aggregation: one wave per dst, 4 edges/step, unroll 2 ------
__global__ __launch_bounds__(256) void k_agg(const uint4* __restrict__ h16x4,
                                             const float* __restrict__ a_src,
                                             const float* __restrict__ a_dst,
                                             const int2* __restrict__ ebounds,
                                             const int* __restrict__ csr2,
                                             const __half* __restrict__ pbuf,
                                             const float* __restrict__ bias,
                                             float* __restrict__ out) {
    int n = (blockIdx.x * 256 + threadIdx.x) >> 6;
    if (n >= N_NODES) return;
    int lane = threadIdx.x & 63;
    int grp = lane >> 4, g = lane & 15, hd = g >> 2;

    float p0 = 0.f;
    if (grp == 0) {
        float e0 = a_src[n * 4 + hd] + a_dst[n * 4 + hd];
        e0 = e0 > 0.f ? e0 : NEG_SLOPE * e0;
        p0 = __expf(e0);                   // self-loop (group 0 only)
    }
    uint4 hs = h16x4[(size_t)n * 16 + g];
    float l  = p0;
    float a0 = p0 * lo2f(hs.x), a1 = p0 * hi2f(hs.x);
    float a2 = p0 * lo2f(hs.y), a3 = p0 * hi2f(hs.y);
    float a4 = p0 * lo2f(hs.z), a5 = p0 * hi2f(hs.z);
    float a6 = p0 * lo2f(hs.w), a7 = p0 * hi2f(hs.w);

    int2 eb = ebounds[n];
    int beg = eb.x, cnt = eb.y - eb.x;
    const int* sp = csr2 + beg + grp;
    const __half* pp = pbuf + (size_t)(beg + grp) * 4 + hd;
    int steps = (cnt + 3) >> 2;
    int t = 0;
    for (; t + 2 <= steps; t += 2) {
        int s0 = sp[4 * t];
        int s1 = sp[4 * t + 4];
        float q0 = __half2float(pp[16 * t]);
        float q1 = __half2float(pp[16 * t + 16]);
        uint4 h0 = h16x4[(size_t)s0 * 16 + g];
        uint4 h1 = h16x4[(size_t)s1 * 16 + g];
        l  += q0 + q1;
        a0 += q0 * lo2f(h0.x) + q1 * lo2f(h1.x);
        a1 += q0 * hi2f(h0.x) + q1 * hi2f(h1.x);
        a2 += q0 * lo2f(h0.y) + q1 * lo2f(h1.y);
        a3 += q0 * hi2f(h0.y) + q1 * hi2f(h1.y);
        a4 += q0 * lo2f(h0.z) + q1 * lo2f(h1.z);
        a5 += q0 * hi2f(h0.z) + q1 * hi2f(h1.z);
        a6 += q0 * lo2f(h0.w) + q1 * lo2f(h1.w);
        a7 += q0 * hi2f(h0.w) + q1 * hi2f(h1.w);
    }
    if (t < steps) {
        int s0 = sp[4 * t];
        float q0 = __half2float(pp[16 * t]);
        uint4 h0 = h16x4[(size_t)s0 * 16 + g];
        l  += q0;
        a0 += q0 * lo2f(h0.x);
        a1 += q0 * hi2f(h0.x);
        a2 += q0 * lo2f(h0.y);
        a3 += q0 * hi2f(h0.y);
        a4 += q0 * lo2f(h0.z);
        a5 += q0 * hi2f(h0.z);
        a6 += q0 * lo2f(h0.w);
        a7 += q0 * hi2f(h0.w);
    }
    #define RED2(v) v += __shfl_xor(v, 16, 64); v += __shfl_xor(v, 32, 64);
    RED2(l); RED2(a0); RED2(a1); RED2(a2); RED2(a3);
    RED2(a4); RED2(a5); RED2(a6); RED2(a7);
    #undef RED2

    if (grp == 0) {
        float inv = 1.f / (l + 1e-16f);
        float4 b0 = *(const float4*)&bias[g * 8];
        float4 b1 = *(const float4*)&bias[g * 8 + 4];
        float o0 = a0 * inv + b0.x, o1 = a1 * inv + b0.y;
        float o2 = a2 * inv + b0.z, o3 = a3 * inv + b0.w;
        float o4 = a4 * inv + b1.x, o5 = a5 * inv + b1.y;
        float o6 = a6 * inv + b1.z, o7 = a7 * inv + b1.w;
        // branchless ELU via fast exp (expm1f libm is ~30 instrs — the R4 VALU hog)
        o0 = o0 > 0.f ? o0 : __expf(o0) - 1.f;
        o1 = o1 > 0.f ? o1 : __expf(o1) - 1.f;
        o2 = o2 > 0.f ? o2 : __expf(o2) - 1.f;
        o3 = o3 > 0.f ? o3 : __expf(o3) - 1.f;
        o4 = o4 > 0.f ? o4 : __expf(o4) - 1.f;
        o5 = o5 > 0.f ? o5 : __expf(o5) - 1.f;
        o6 = o6 > 0.f ? o6 : __expf(o6) - 1.f;
        o7 = o7 > 0.f ? o7 : __expf(o7) - 1.f;
        *(float4*)&out[(size_t)n * F_DIM + g * 8]     = make_float4(o0, o1, o2, o3);
        *(float4*)&out[(size_t)n * F_DIM + g * 8 + 4] = make_float4(o4, o5, o6, o7);
    }
}

extern "C" void kernel_launch(void* const* d_in, const int* in_sizes, int n_in,
                              void* d_out, int out_size, void* d_ws, size_t ws_size,
                              hipStream_t stream) {
    const float* x       = (const float*)d_in[0];
    const int*   ei      = (const int*)d_in[1];   // (2, E) row-major int32
    const float* W       = (const float*)d_in[2];
    const float* att_src = (const float*)d_in[3];
    const float* att_dst = (const float*)d_in[4];
    const float* bias    = (const float*)d_in[5];
    float*       out     = (float*)d_out;

    char* ws = (char*)d_ws;
    unsigned short* h16 = (unsigned short*)ws; ws += (size_t)N_NODES * F_DIM * 2;   // 25.6 MB
    unsigned short* Wt  = (unsigned short*)ws; ws += (size_t)IN_DIM * F_DIM * 2;    // 32 KB
    float* a_src  = (float*)ws; ws += (size_t)N_NODES * 4 * 4;
    float* a_dst  = (float*)ws; ws += (size_t)N_NODES * 4 * 4;
    int*   G      = (int*)ws;   ws += (size_t)G_TOT * 4;                            // 0.4 MB
    int*   part   = (int*)ws;   ws += 1024;
    int*   boff   = (int*)ws;   ws += 4096;
    int2*  ebounds= (int2*)ws;  ws += (size_t)N_NODES * 8 + 512;
    int*   ebuf   = (int*)ws;   ws += (size_t)N_EDGES * 4;                          // 6.4 MB
    int*   csr2   = (int*)ws;   ws += (size_t)CSR_CAP * 4;                          // 7.6 MB
    __half* pbuf  = (__half*)ws; ws += (size_t)CSR_CAP * 4 * 2;                     // 15.2 MB

    k_wprep<<<64, 256, 0, stream>>>(W, Wt);
    k_gemm<<<(N_NODES + 63) / 64, 256, 0, stream>>>(x, Wt, h16, att_src, att_dst, a_src, a_dst);

    k_bhist<<<NBLK, 256, 0, stream>>>(ei + N_EDGES, G);
    k_scanp<<<SC_NB, 256, 0, stream>>>(G, part);
    k_scant<<<1, 64, 0, stream>>>(part, boff);
    k_scand<<<SC_NB, 256, 0, stream>>>(G, part, boff);
    k_bscat<<<NBLK, 256, 0, stream>>>(ei, G, ebuf);
    k_csrfin<<<NBUCK, 256, 0, stream>>>(ebuf, boff, a_src, a_dst, ebounds, csr2, pbuf);

    k_agg<<<(N_NODES * 64 + 255) / 256, 256, 0, stream>>>((const uint4*)h16, a_src, a_dst, ebounds, csr2, pbuf, bias, out);
}